// Round 2
// baseline (32998.630 us; speedup 1.0000x reference)
//
#include <hip/hip_runtime.h>

// Problem constants (from reference)
constexpr int kV = 50000, kH = 512, kE = 4, kF = 2048, kRH = 2560, kSTEPS = 3;
constexpr int kMAXIT = 20;
constexpr int kNT = 1024;                 // B*S tokens
constexpr float kTOL2 = 1e-6f;            // TOL^2

// ============================ init ============================
__global__ void init_kernel(float* h, float* norm2, int* flags) {
    int i = blockIdx.x * 256 + threadIdx.x;
    if (i < kNT * kH) h[i] = 0.f;
    if (i == 0) { *norm2 = 0.f; flags[0] = 0; flags[1] = 0; flags[2] = 0; } // done, iters, zeroflag
}

// ====================== spectral norm (1 block) ======================
__device__ __forceinline__ float block_sum_512(float x, float* red) {
    int j = threadIdx.x;
    red[j] = x;
    for (int s = 256; s > 0; s >>= 1) { __syncthreads(); if (j < s) red[j] += red[j + s]; }
    __syncthreads();
    float r = red[0];
    __syncthreads();
    return r;
}

__global__ __launch_bounds__(512) void spectral_kernel(const float* __restrict__ W,
                                                       float* __restrict__ Wsn) {
    __shared__ float su[kH], sv[kH], red[kH];
    const int j = threadIdx.x;
    su[j] = 1.0f / sqrtf((float)kH);
    __syncthreads();
    for (int it = 0; it < 31; ++it) {
        // v = normalize(W^T u)
        float acc = 0.f;
        for (int i = 0; i < kH; ++i) acc += W[i * kH + j] * su[i];
        float nv = sqrtf(block_sum_512(acc * acc, red)) + 1e-12f;
        sv[j] = acc / nv;
        __syncthreads();
        if (it == 30) break;               // reference: 30 (v,u) rounds, then one extra v
        // u = normalize(W v)
        float acc2 = 0.f;
        for (int k2 = 0; k2 < kH; ++k2) acc2 += W[j * kH + k2] * sv[k2];
        float nu = sqrtf(block_sum_512(acc2 * acc2, red)) + 1e-12f;
        su[j] = acc2 / nu;
        __syncthreads();
    }
    // sigma = u . (W v)
    float wv = 0.f;
    for (int k2 = 0; k2 < kH; ++k2) wv += W[j * kH + k2] * sv[k2];
    float sigma = block_sum_512(su[j] * wv, red);
    float inv = 1.0f / sigma;
    for (int i = j; i < kH * kH; i += kH) Wsn[i] = W[i] * inv;
}

// ============================ embed ============================
__global__ void embed_kernel(const int* __restrict__ x, const float* __restrict__ emb,
                             float* __restrict__ e) {
    int i = blockIdx.x * 256 + threadIdx.x;       // float4 index
    if (i >= kNT * kH / 4) return;
    int t = i >> 7, d4 = i & 127;
    float4 v = ((const float4*)(emb + (size_t)x[t] * kH))[d4];
    ((float4*)(e + (size_t)t * kH))[d4] = v;
}

// ============================ GEMM ============================
// C[m,n] = act( sum_k A[m,k]*B(k,n) + bias[n] + Add[m,n] )
// BT=true : B is (N,K) row-major (i.e. multiply by B^T), ldb = row stride
// BT=false: B is (K,N) row-major
// MOE=true: blockIdx.z selects expert; M=counts[e], rows offset by offsets[e];
//           A row gathered via rowlist (if non-null), C row = offsets[e]+r.
template<bool BT, bool RELU, bool BIAS, bool ADD, bool MOE>
__global__ __launch_bounds__(256)
void gemm_f32(const float* __restrict__ A, int lda,
              const float* __restrict__ B, int ldb, long strideB,
              const float* __restrict__ bias,
              const float* __restrict__ Add, int ldadd,
              float* __restrict__ C, int ldc,
              int M, int N, int K,
              const int* __restrict__ rowlist,
              const int* __restrict__ counts,
              const int* __restrict__ offsets,
              const int* __restrict__ done)
{
    if (done && *done) return;
    int base = 0;
    if (MOE) {
        const int e = blockIdx.z;
        M = counts[e];
        base = offsets[e];
        B += (long)e * strideB;
    }
    const int bm = blockIdx.x * 64;
    if (bm >= M) return;
    const int bn = blockIdx.y * 64;

    __shared__ float As[32][68];   // k-major, +4 pad: aligned b128 reads, reduced write conflicts
    __shared__ float Bs[32][68];
    const int tid = threadIdx.x;
    const int tx = tid & 15, ty = tid >> 4;
    float acc[4][4] = {};

    for (int k0 = 0; k0 < K; k0 += 32) {
        #pragma unroll
        for (int it = 0; it < 2; ++it) {
            const int idx = tid + it * 256;
            const int row = idx >> 3;
            const int kq  = (idx & 7) << 2;
            float4 v = make_float4(0.f, 0.f, 0.f, 0.f);
            const int r = bm + row;
            if (r < M) {
                long ar;
                if (MOE) ar = rowlist ? (long)rowlist[base + r] : (long)(base + r);
                else     ar = r;
                v = *(const float4*)(A + ar * (long)lda + k0 + kq);
            }
            As[kq + 0][row] = v.x; As[kq + 1][row] = v.y;
            As[kq + 2][row] = v.z; As[kq + 3][row] = v.w;
        }
        if (BT) {
            #pragma unroll
            for (int it = 0; it < 2; ++it) {
                const int idx = tid + it * 256;
                const int col = idx >> 3;
                const int kq  = (idx & 7) << 2;
                float4 v = make_float4(0.f, 0.f, 0.f, 0.f);
                const int c = bn + col;
                if (c < N) v = *(const float4*)(B + (long)c * ldb + k0 + kq);
                Bs[kq + 0][col] = v.x; Bs[kq + 1][col] = v.y;
                Bs[kq + 2][col] = v.z; Bs[kq + 3][col] = v.w;
            }
        } else {
            #pragma unroll
            for (int it = 0; it < 2; ++it) {
                const int idx = tid + it * 256;
                const int kk = idx >> 4;
                const int c4 = (idx & 15) << 2;
                float4 v = make_float4(0.f, 0.f, 0.f, 0.f);
                if (bn + c4 + 3 < N) v = *(const float4*)(B + (long)(k0 + kk) * ldb + bn + c4);
                *(float4*)&Bs[kk][c4] = v;
            }
        }
        __syncthreads();
        #pragma unroll
        for (int kk = 0; kk < 32; ++kk) {
            const float4 av = *(const float4*)&As[kk][ty << 2];
            const float4 bv = *(const float4*)&Bs[kk][tx << 2];
            const float a4[4] = {av.x, av.y, av.z, av.w};
            const float b4[4] = {bv.x, bv.y, bv.z, bv.w};
            #pragma unroll
            for (int i = 0; i < 4; ++i)
                #pragma unroll
                for (int jj = 0; jj < 4; ++jj)
                    acc[i][jj] += a4[i] * b4[jj];
        }
        __syncthreads();
    }

    const int row0 = bm + (ty << 2);
    const int col0 = bn + (tx << 2);
    #pragma unroll
    for (int i = 0; i < 4; ++i) {
        const int gr = row0 + i;
        if (gr >= M) continue;
        const long crow = MOE ? (long)(base + gr) : (long)gr;
        #pragma unroll
        for (int jj = 0; jj < 4; ++jj) {
            const int gc = col0 + jj;
            if (gc >= N) continue;
            float cv = acc[i][jj];
            if (BIAS) cv += bias[gc];
            if (ADD)  cv += Add[(long)gr * ldadd + gc];
            if (RELU) cv = fmaxf(cv, 0.f);
            C[crow * ldc + gc] = cv;
        }
    }
}

// ============================ MoE routing ============================
__global__ __launch_bounds__(256) void route_kernel(const float* __restrict__ h,
    const float* __restrict__ rw, int* __restrict__ esel, float* __restrict__ wsel,
    int* __restrict__ counts, const int* __restrict__ done) {
    if (*done) return;
    int t = blockIdx.x * 4 + (threadIdx.x >> 6);
    int lane = threadIdx.x & 63;
    const float* hr = h + (long)t * kH;
    float l[4] = {0.f, 0.f, 0.f, 0.f};
    for (int j = lane; j < kH; j += 64) {
        float hv = hr[j];
        #pragma unroll
        for (int e = 0; e < kE; ++e) l[e] += hv * rw[e * kH + j];
    }
    #pragma unroll
    for (int e = 0; e < kE; ++e)
        #pragma unroll
        for (int off = 32; off; off >>= 1) l[e] += __shfl_xor(l[e], off);
    if (lane == 0) {
        int i0 = 0;
        #pragma unroll
        for (int e = 1; e < kE; ++e) if (l[e] > l[i0]) i0 = e;
        int i1 = -1;
        #pragma unroll
        for (int e = 0; e < kE; ++e) { if (e == i0) continue; if (i1 < 0 || l[e] > l[i1]) i1 = e; }
        // top-2 softmax ratio == renormalized top-2 of softmax over 4
        float m  = l[i0];
        float e1 = expf(l[i1] - m);
        float s  = 1.f + e1;
        esel[2 * t] = i0; esel[2 * t + 1] = i1;
        wsel[2 * t] = 1.f / s; wsel[2 * t + 1] = e1 / s;
        atomicAdd(&counts[i0], 1);
        atomicAdd(&counts[i1], 1);
    }
}

__global__ void prep_kernel(int* counts, int* cursor) {
    int i = threadIdx.x;
    if (i < kE) { counts[i] = 0; cursor[i] = 0; }
}

__global__ void offsets_kernel(const int* counts, int* offs) {
    if (threadIdx.x == 0) {
        int o = 0;
        for (int e = 0; e < kE; ++e) { offs[e] = o; o += counts[e]; }
    }
}

__global__ void scatter_kernel(const int* __restrict__ esel, const int* __restrict__ offs,
                               int* __restrict__ cursor, int* __restrict__ ptok,
                               int* __restrict__ ppos, const int* __restrict__ done) {
    if (*done) return;
    int t = blockIdx.x * 256 + threadIdx.x;
    if (t >= kNT) return;
    #pragma unroll
    for (int s = 0; s < 2; ++s) {
        int e = esel[2 * t + s];
        int pos = offs[e] + atomicAdd(&cursor[e], 1);
        ptok[pos] = t;
        ppos[2 * t + s] = pos;
    }
}

__global__ void moe_combine_kernel(const float* __restrict__ pout, const float* __restrict__ wsel,
                                   const int* __restrict__ ppos, float* __restrict__ moe,
                                   const int* __restrict__ done) {
    if (*done) return;
    int i = blockIdx.x * 256 + threadIdx.x;
    if (i >= kNT * kH / 4) return;
    int t = i >> 7, d4 = i & 127;
    float w0 = wsel[2 * t], w1 = wsel[2 * t + 1];
    long p0 = ppos[2 * t], p1 = ppos[2 * t + 1];
    float4 a = ((const float4*)(pout + p0 * kH))[d4];
    float4 b = ((const float4*)(pout + p1 * kH))[d4];
    float4 o;
    o.x = w0 * a.x + w1 * b.x; o.y = w0 * a.y + w1 * b.y;
    o.z = w0 * a.z + w1 * b.z; o.w = w0 * a.w + w1 * b.w;
    ((float4*)(moe + (long)t * kH))[d4] = o;
}

// ======================= reasoning top-K (K=32 of 512) =======================
__global__ __launch_bounds__(256) void topk_kernel(const float* __restrict__ scores,
                                                   float* __restrict__ z,
                                                   const int* __restrict__ done) {
    if (*done) return;
    int t = blockIdx.x * 4 + (threadIdx.x >> 6);
    int lane = threadIdx.x & 63;
    const float* srow = scores + (long)t * kH;
    float4 va = ((const float4*)srow)[lane * 2];
    float4 vb = ((const float4*)srow)[lane * 2 + 1];
    float v[8] = {va.x, va.y, va.z, va.w, vb.x, vb.y, vb.z, vb.w};
    unsigned used = 0u;
    float vmax0 = 0.f, expsum = 0.f;
    for (int k = 0; k < 32; ++k) {
        float bv = -3.0e38f; int bidx = 1 << 30;
        #pragma unroll
        for (int jj = 0; jj < 8; ++jj) {
            bool ok = !((used >> jj) & 1u);
            if (ok && v[jj] > bv) { bv = v[jj]; bidx = lane * 8 + jj; }
        }
        #pragma unroll
        for (int off = 32; off; off >>= 1) {
            float ov = __shfl_xor(bv, off);
            int   oi = __shfl_xor(bidx, off);
            if (ov > bv || (ov == bv && oi < bidx)) { bv = ov; bidx = oi; }
        }
        if (k == 0) vmax0 = bv;
        expsum += expf(bv - vmax0);
        if ((bidx >> 3) == lane) used |= 1u << (bidx & 7);
    }
    float4 za = ((const float4*)(z + (long)t * kH))[lane * 2];
    float4 zb = ((const float4*)(z + (long)t * kH))[lane * 2 + 1];
    float zz[8] = {za.x, za.y, za.z, za.w, zb.x, zb.y, zb.z, zb.w};
    #pragma unroll
    for (int jj = 0; jj < 8; ++jj) {
        float w = ((used >> jj) & 1u) ? (expf(v[jj] - vmax0) / expsum) : 0.f;
        zz[jj] *= w;
    }
    float4 oa = make_float4(zz[0], zz[1], zz[2], zz[3]);
    float4 ob = make_float4(zz[4], zz[5], zz[6], zz[7]);
    ((float4*)(z + (long)t * kH))[lane * 2] = oa;
    ((float4*)(z + (long)t * kH))[lane * 2 + 1] = ob;
}

// ======================= combine + norm =======================
__global__ void combine_kernel(const float* __restrict__ hWp, const float* __restrict__ exp_,
                               const float* __restrict__ moe, const float* __restrict__ reas,
                               const float* __restrict__ h, float* __restrict__ hnew,
                               float* __restrict__ norm2, const int* __restrict__ done) {
    if (*done) return;
    int i = blockIdx.x * 256 + threadIdx.x;
    float local = 0.f;
    if (i < kNT * kH / 4) {
        float4 a = ((const float4*)hWp)[i];
        float4 b = ((const float4*)exp_)[i];
        float4 c = ((const float4*)moe)[i];
        float4 d = ((const float4*)reas)[i];
        float4 hv = ((const float4*)h)[i];
        float4 v;
        v.x = fmaxf(a.x + b.x + c.x + d.x, 0.f);
        v.y = fmaxf(a.y + b.y + c.y + d.y, 0.f);
        v.z = fmaxf(a.z + b.z + c.z + d.z, 0.f);
        v.w = fmaxf(a.w + b.w + c.w + d.w, 0.f);
        ((float4*)hnew)[i] = v;
        float dx = v.x - hv.x, dy = v.y - hv.y, dz = v.z - hv.z, dw = v.w - hv.w;
        local = dx * dx + dy * dy + dz * dz + dw * dw;
    }
    #pragma unroll
    for (int off = 32; off; off >>= 1) local += __shfl_xor(local, off);
    __shared__ float red[4];
    int lane = threadIdx.x & 63, wv = threadIdx.x >> 6;
    if (lane == 0) red[wv] = local;
    __syncthreads();
    if (threadIdx.x == 0) atomicAdd(norm2, red[0] + red[1] + red[2] + red[3]);
}

__global__ void check_kernel(float* norm2, int* done, int* iters, int k) {
    if (threadIdx.x == 0) {
        if (!*done) {
            if (*norm2 < kTOL2) *done = 1;
            else *iters = k + 1;
        }
        *norm2 = 0.f;
    }
}

__global__ void iters_out_kernel(const int* iters, float* dst) {
    if (threadIdx.x == 0) dst[0] = (float)(*iters);
}

// ============================ launch ============================
extern "C" void kernel_launch(void* const* d_in, const int* in_sizes, int n_in,
                              void* d_out, int out_size, void* d_ws, size_t ws_size,
                              hipStream_t stream)
{
    const int*   x    = (const int*)  d_in[0];
    const float* emb  = (const float*)d_in[1];
    const float* W_h  = (const float*)d_in[2];
    const float* W_x  = (const float*)d_in[3];
    const float* rw   = (const float*)d_in[4];
    const float* ew1  = (const float*)d_in[5];
    const float* ew2  = (const float*)d_in[6];
    const float* T1w  = (const float*)d_in[7];
    const float* T1b  = (const float*)d_in[8];
    const float* T2w  = (const float*)d_in[9];
    const float* T2b  = (const float*)d_in[10];
    const float* R1w  = (const float*)d_in[11];
    const float* R1b  = (const float*)d_in[12];
    const float* R2w  = (const float*)d_in[13];
    const float* R2b  = (const float*)d_in[14];
    const float* outw = (const float*)d_in[15];
    const float* outb = (const float*)d_in[16];
    float* out = (float*)d_out;

    float* w      = (float*)d_ws;
    float* Wsn    = w;                       // 512*512
    float* e      = Wsn    + 262144;         // 1024*512
    float* ex     = e      + 524288;
    float* h      = ex     + 524288;
    float* hnew   = h      + 524288;
    float* hWb    = hnew   + 524288;
    float* moe    = hWb    + 524288;
    float* reas   = moe    + 524288;
    float* z      = reas   + 524288;
    float* hT1h   = z      + 524288;         // 1024*2560
    float* a1     = hT1h   + 2621440;        // 1024*2560
    float* sc     = a1     + 2621440;        // 1024*512
    float* hidden = sc     + 524288;         // 2048*2048
    float* pout   = hidden + 4194304;        // 2048*512
    float* wsel   = pout   + 1048576;        // 2048
    float* norm2  = wsel   + 2048;           // 1 (+pad)
    int* ints     = (int*)(norm2 + 16);
    int* done     = ints + 0;
    int* iters    = ints + 1;
    int* zflag    = ints + 2;
    int* counts   = ints + 4;
    int* offs     = ints + 8;
    int* cursor   = ints + 12;
    int* esel     = ints + 16;
    int* ppos     = ints + 16 + 2048;
    int* ptok     = ints + 16 + 4096;

    init_kernel<<<dim3(2048), dim3(256), 0, stream>>>(h, norm2, ints);
    spectral_kernel<<<dim3(1), dim3(512), 0, stream>>>(W_h, Wsn);
    embed_kernel<<<dim3(512), dim3(256), 0, stream>>>(x, emb, e);
    // ex = e @ W_x^T  (loop-invariant)
    gemm_f32<true, false, false, false, false><<<dim3(16, 8), dim3(256), 0, stream>>>(
        e, kH, W_x, kH, 0, nullptr, nullptr, 0, ex, kH, kNT, kH, kH,
        nullptr, nullptr, nullptr, nullptr);

    auto run_step = [&](const int* df) {
        // hW = h @ Wsn^T
        gemm_f32<true, false, false, false, false><<<dim3(16, 8), dim3(256), 0, stream>>>(
            h, kH, Wsn, kH, 0, nullptr, nullptr, 0, hWb, kH, kNT, kH, kH,
            nullptr, nullptr, nullptr, df);
        // --- MoE (top-2 only) ---
        prep_kernel<<<dim3(1), dim3(64), 0, stream>>>(counts, cursor);
        route_kernel<<<dim3(256), dim3(256), 0, stream>>>(h, rw, esel, wsel, counts, df);
        offsets_kernel<<<dim3(1), dim3(64), 0, stream>>>(counts, offs);
        scatter_kernel<<<dim3(4), dim3(256), 0, stream>>>(esel, offs, cursor, ptok, ppos, df);
        gemm_f32<false, true, false, false, true><<<dim3(16, 32, 4), dim3(256), 0, stream>>>(
            h, kH, ew1, kF, (long)kH * kF, nullptr, nullptr, 0, hidden, kF,
            2 * kNT, kF, kH, ptok, counts, offs, df);
        gemm_f32<false, false, false, false, true><<<dim3(16, 8, 4), dim3(256), 0, stream>>>(
            hidden, kF, ew2, kH, (long)kF * kH, nullptr, nullptr, 0, pout, kH,
            2 * kNT, kH, kF, nullptr, counts, offs, df);
        moe_combine_kernel<<<dim3(512), dim3(256), 0, stream>>>(pout, wsel, ppos, moe, df);
        // --- reasoning ---
        // hT1h = h @ T1_w[:, H:]^T + T1_b  (invariant across the 3 sub-steps)
        gemm_f32<true, false, true, false, false><<<dim3(16, 40), dim3(256), 0, stream>>>(
            h, kH, T1w + kH, 2 * kH, 0, T1b, nullptr, 0, hT1h, kRH, kNT, kRH, kH,
            nullptr, nullptr, nullptr, df);
        hipMemcpyAsync(z, h, sizeof(float) * kNT * kH, hipMemcpyDeviceToDevice, stream);
        for (int r = 0; r < kSTEPS; ++r) {
            gemm_f32<true, true, false, true, false><<<dim3(16, 40), dim3(256), 0, stream>>>(
                z, kH, T1w, 2 * kH, 0, nullptr, hT1h, kRH, a1, kRH, kNT, kRH, kH,
                nullptr, nullptr, nullptr, df);
            gemm_f32<true, false, true, false, false><<<dim3(16, 8), dim3(256), 0, stream>>>(
                a1, kRH, T2w, kRH, 0, T2b, nullptr, 0, sc, kH, kNT, kH, kRH,
                nullptr, nullptr, nullptr, df);
            topk_kernel<<<dim3(256), dim3(256), 0, stream>>>(sc, z, df);
        }
        gemm_f32<true, true, true, false, false><<<dim3(16, 40), dim3(256), 0, stream>>>(
            z, kH, R1w, kH, 0, R1b, nullptr, 0, a1, kRH, kNT, kRH, kH,
            nullptr, nullptr, nullptr, df);
        gemm_f32<true, false, true, false, false><<<dim3(16, 8), dim3(256), 0, stream>>>(
            a1, kRH, R2w, kRH, 0, R2b, nullptr, 0, reas, kH, kNT, kH, kRH,
            nullptr, nullptr, nullptr, df);
        combine_kernel<<<dim3(512), dim3(256), 0, stream>>>(hWb, ex, moe, reas, h, hnew, norm2, df);
    };

    for (int k = 0; k < kMAXIT; ++k) {
        run_step(done);
        check_kernel<<<dim3(1), dim3(1), 0, stream>>>(norm2, done, iters, k);
        hipMemcpyAsync(h, hnew, sizeof(float) * kNT * kH, hipMemcpyDeviceToDevice, stream);
    }
    run_step(zflag);   // h_star = step(h), unconditional

    // logits = h_star @ out_w^T + out_b
    gemm_f32<true, false, true, false, false><<<dim3(16, 782), dim3(256), 0, stream>>>(
        hnew, kH, outw, kH, 0, outb, nullptr, 0, out, kV, kNT, kV, kH,
        nullptr, nullptr, nullptr, nullptr);
    iters_out_kernel<<<dim3(1), dim3(64), 0, stream>>>(iters, out + (out_size - 1));
}